// Round 1
// 1506.955 us; speedup vs baseline: 1.1523x; 1.1523x over previous
//
#include <hip/hip_runtime.h>

// Problem constants (inputs fixed by harness: text [64,512] f32, spots [500000,512] f32, top_k=10)
#define B_TEXT 64
#define D_DIM  512
#define TOPK   10
#define TILE_N 128           // spot rows per block in GEMM
#define BK     64            // K-chunk
#define CH     16            // top-k chunks per text row

typedef short bf16x8 __attribute__((ext_vector_type(8)));
typedef float f32x4  __attribute__((ext_vector_type(4)));

__device__ __forceinline__ unsigned short f2bf(float x) {
    unsigned u = __float_as_uint(x);
    u += 0x7fffu + ((u >> 16) & 1u);          // RNE
    return (unsigned short)(u >> 16);
}
__device__ __forceinline__ float bf2f(unsigned short h) {
    return __uint_as_float(((unsigned)h) << 16);
}

// XOR-swizzled u16 index for a [rows][64] u16 tile (128 B rows = 8 x 16B slots).
// slot ^= (row & 7): keeps 16B alignment, removes pad (48.5 KB total -> 3 blocks/CU),
// read pattern stays balanced at 8 lanes / 4-bank group (= LDS BW floor, same as old +8 pad).
__device__ __forceinline__ int swz(int row, int k) {
    return row * 64 + ((((k >> 3) ^ (row & 7)) << 3) | (k & 7));
}

// ---------------- K1: normalize text rows, split into bf16 hi/lo ----------------
__global__ void prep_text(const float* __restrict__ T, unsigned short* __restrict__ tHi,
                          unsigned short* __restrict__ tLo) {
    int b = blockIdx.x;
    int lane = threadIdx.x;                    // 64 threads = 1 wave
    const float* row = T + b * D_DIM;
    float4 a = *(const float4*)(row + lane * 4);
    float4 c = *(const float4*)(row + 256 + lane * 4);
    float p = a.x*a.x + a.y*a.y + a.z*a.z + a.w*a.w
            + c.x*c.x + c.y*c.y + c.z*c.z + c.w*c.w;
    #pragma unroll
    for (int off = 1; off < 64; off <<= 1) p += __shfl_xor(p, off);
    float inv = 1.0f / fmaxf(sqrtf(p), 1e-12f);
    float v[8] = {a.x, a.y, a.z, a.w, c.x, c.y, c.z, c.w};
    #pragma unroll
    for (int j = 0; j < 8; ++j) {
        float y = v[j] * inv;
        unsigned short hi = f2bf(y);
        unsigned short lo = f2bf(y - bf2f(hi));   // x - bf16(x) is exact in f32
        int col = (j < 4) ? (lane * 4 + j) : (256 + lane * 4 + (j - 4));
        tHi[b * D_DIM + col] = hi;
        tLo[b * D_DIM + col] = lo;
    }
}

// ---------------- K2: scores = (unit text) . spots^T / ||spot||, split-bf16 MFMA ----------------
// Tile: 64(m) x 128(n), K chunked by 64. 4 waves, wave w owns n in [w*32, w*32+32).
// Pipelined (T14 async-STAGE): chunk k+1's HBM loads are issued BEFORE chunk k's MFMA phase,
// conversion happens after MFMA but before the barrier; only ds_writes sit between barriers.
// LDS swizzled (no pad): 48.5 KB -> 3 blocks/CU; __launch_bounds__(256,3) caps VGPR ~170.
__global__ __launch_bounds__(256, 3) void gemm_scores(
    const float* __restrict__ S, const unsigned short* __restrict__ tHi,
    const unsigned short* __restrict__ tLo, float* __restrict__ out, int N) {

    __shared__ __align__(16) unsigned short As_hi[B_TEXT * 64];
    __shared__ __align__(16) unsigned short As_lo[B_TEXT * 64];
    __shared__ __align__(16) unsigned short Bs_hi[TILE_N * 64];
    __shared__ __align__(16) unsigned short Bs_lo[TILE_N * 64];
    __shared__ float s_ss[TILE_N];             // per-spot-row sum of squares (written once, post-loop)

    const int tid  = threadIdx.x;
    const int n0   = blockIdx.x * TILE_N;
    const int lane = tid & 63;
    const int w    = tid >> 6;
    const int l15  = lane & 15;
    const int quad = lane >> 4;

    // A staging: thread -> text row, 16 u16 per matrix
    const int arow = tid >> 2;
    const int akq  = (tid & 3) << 4;
    // B staging: fixed col range per thread, row strides by 16 across i
    const int bk   = (tid & 15) << 2;          // col within chunk (x4 floats)
    const int br0  = tid >> 4;                 // row = i*16 + br0

    f32x4 acc[4][2];
    const f32x4 zf = {0.f, 0.f, 0.f, 0.f};
    #pragma unroll
    for (int i = 0; i < 4; ++i)
        #pragma unroll
        for (int j = 0; j < 2; ++j) acc[i][j] = zf;

    float ssq[8];
    #pragma unroll
    for (int i = 0; i < 8; ++i) ssq[i] = 0.0f;

    float4 bv[8];                              // in-flight B chunk (f32)
    uint4 a_h0, a_h1, a_l0, a_l1;              // in-flight A chunk (pre-split bf16)
    ushort4 hh[8], ll[8];                      // converted B chunk

    auto issue = [&](int kc) {                 // fire HBM/L2 loads, no wait
        const uint4* ph = (const uint4*)(tHi + arow * D_DIM + kc + akq);
        const uint4* pl = (const uint4*)(tLo + arow * D_DIM + kc + akq);
        a_h0 = ph[0]; a_h1 = ph[1];
        a_l0 = pl[0]; a_l1 = pl[1];
        const float* sp = S + (size_t)(n0 + br0) * D_DIM + kc + bk;
        #pragma unroll
        for (int i = 0; i < 8; ++i) {
            int r = i * 16 + br0;
            if (n0 + r < N) bv[i] = *(const float4*)(sp + (size_t)i * 16 * D_DIM);
            else            bv[i] = make_float4(0.f, 0.f, 0.f, 0.f);
        }
    };

    auto convert = [&]() {                     // register-only: bf16 hi/lo split + fused sumsq
        #pragma unroll
        for (int i = 0; i < 8; ++i) {
            float4 v = bv[i];
            ushort4 h, l;
            h.x = f2bf(v.x); l.x = f2bf(v.x - bf2f(h.x));
            h.y = f2bf(v.y); l.y = f2bf(v.y - bf2f(h.y));
            h.z = f2bf(v.z); l.z = f2bf(v.z - bf2f(h.z));
            h.w = f2bf(v.w); l.w = f2bf(v.w - bf2f(h.w));
            hh[i] = h; ll[i] = l;
            float p = v.x*v.x + v.y*v.y + v.z*v.z + v.w*v.w;
            p += __shfl_xor(p, 1);
            p += __shfl_xor(p, 2);
            p += __shfl_xor(p, 4);
            p += __shfl_xor(p, 8);             // 16 lanes share a row -> row-chunk sum
            ssq[i] += p;                       // same thread owns (i, br0) every chunk
        }
    };

    auto stage_write = [&]() {                 // LDS writes only (between barriers)
        *(uint4*)&As_hi[swz(arow, akq)]     = a_h0;
        *(uint4*)&As_hi[swz(arow, akq + 8)] = a_h1;
        *(uint4*)&As_lo[swz(arow, akq)]     = a_l0;
        *(uint4*)&As_lo[swz(arow, akq + 8)] = a_l1;
        #pragma unroll
        for (int i = 0; i < 8; ++i) {
            int r = i * 16 + br0;
            *(ushort4*)&Bs_hi[swz(r, bk)] = hh[i];
            *(ushort4*)&Bs_lo[swz(r, bk)] = ll[i];
        }
    };

    // prologue: stage chunk 0
    issue(0);
    convert();
    stage_write();
    __syncthreads();

    for (int kc = 0; kc < D_DIM; kc += BK) {
        const bool more = (kc + BK) < D_DIM;
        if (more) issue(kc + BK);              // loads in flight across the MFMA phase

        // ---- MFMA: acc += hi*hi + hi*lo + lo*hi (split-f32 precision) ----
        #pragma unroll
        for (int ks = 0; ks < 2; ++ks) {
            const int off = ks * 32 + quad * 8;
            bf16x8 ah[4], al[4], bh[2], bl[2];
            #pragma unroll
            for (int mt = 0; mt < 4; ++mt) {
                int m = mt * 16 + l15;
                ah[mt] = *(const bf16x8*)&As_hi[swz(m, off)];
                al[mt] = *(const bf16x8*)&As_lo[swz(m, off)];
            }
            #pragma unroll
            for (int nt = 0; nt < 2; ++nt) {
                int nl = w * 32 + nt * 16 + l15;
                bh[nt] = *(const bf16x8*)&Bs_hi[swz(nl, off)];
                bl[nt] = *(const bf16x8*)&Bs_lo[swz(nl, off)];
            }
            #pragma unroll
            for (int mt = 0; mt < 4; ++mt)
                #pragma unroll
                for (int nt = 0; nt < 2; ++nt) {
                    acc[mt][nt] = __builtin_amdgcn_mfma_f32_16x16x32_bf16(ah[mt], bh[nt], acc[mt][nt], 0, 0, 0);
                    acc[mt][nt] = __builtin_amdgcn_mfma_f32_16x16x32_bf16(ah[mt], bl[nt], acc[mt][nt], 0, 0, 0);
                    acc[mt][nt] = __builtin_amdgcn_mfma_f32_16x16x32_bf16(al[mt], bh[nt], acc[mt][nt], 0, 0, 0);
                }
        }

        if (more) {
            convert();                         // overlaps other waves' MFMA tail; waits vmcnt here
            __syncthreads();                   // all waves done reading current LDS chunk
            stage_write();
            __syncthreads();                   // next chunk staged
        }
    }

    // publish sum-of-squares (each (i,br0) slot has a unique owner)
    if ((tid & 15) == 0) {
        #pragma unroll
        for (int i = 0; i < 8; ++i) s_ss[i * 16 + br0] = ssq[i];
    }
    __syncthreads();

    // ---- epilogue: scale by 1/max(||s||,eps), store ----
    #pragma unroll
    for (int nt = 0; nt < 2; ++nt) {
        int nl = w * 32 + nt * 16 + l15;
        int n  = n0 + nl;
        if (n >= N) continue;
        float inv = 1.0f / fmaxf(sqrtf(s_ss[nl]), 1e-12f);
        #pragma unroll
        for (int mt = 0; mt < 4; ++mt) {
            #pragma unroll
            for (int r = 0; r < 4; ++r) {
                int m = mt * 16 + quad * 4 + r;
                out[(size_t)m * N + n] = acc[mt][nt][r] * inv;
            }
        }
    }
}

// ---------------- K3: per (row, chunk) partial top-10 ----------------
__global__ __launch_bounds__(256) void topk_part(
    const float* __restrict__ scores, float* __restrict__ cs, int* __restrict__ ci, int N) {
    const int b = blockIdx.y;
    const int c = blockIdx.x;
    const int t = threadIdx.x;
    const int chunk = (((N + CH - 1) / CH) + 3) & ~3;   // multiple of 4 -> float4-aligned bases
    const int base  = c * chunk;
    const float* row = scores + (size_t)b * N;

    float ts[TOPK]; int ti[TOPK];
    #pragma unroll
    for (int j = 0; j < TOPK; ++j) { ts[j] = -3.4e38f; ti[j] = 0x7fffffff; }

    for (int e = t * 4; e < chunk; e += 1024) {
        int n = base + e;
        if (n >= N) break;
        float4 v4;
        if (n + 3 < N) {
            v4 = *(const float4*)(row + n);
        } else {
            v4.x = row[n];
            v4.y = (n + 1 < N) ? row[n + 1] : -3.4e38f;
            v4.z = (n + 2 < N) ? row[n + 2] : -3.4e38f;
            v4.w = (n + 3 < N) ? row[n + 3] : -3.4e38f;
        }
        float vv[4] = {v4.x, v4.y, v4.z, v4.w};
        #pragma unroll
        for (int q = 0; q < 4; ++q) {
            float v = vv[q];
            if (v > ts[TOPK - 1]) {             // strict >: first-seen (lower idx) wins ties
                float cv = v; int cidx = n + q;
                #pragma unroll
                for (int j = 0; j < TOPK; ++j) { // bubble into sorted-desc list (static indices only)
                    bool g = (cv > ts[j]);
                    float ns = g ? cv : ts[j]; int ni = g ? cidx : ti[j];
                    cv = g ? ts[j] : cv; cidx = g ? ti[j] : cidx;
                    ts[j] = ns; ti[j] = ni;
                }
            }
        }
    }

    // spill sorted lists to LDS (dynamic 'ptr' indexing must not touch registers)
    __shared__ float all_s[256][TOPK];
    __shared__ int   all_i[256][TOPK];
    #pragma unroll
    for (int j = 0; j < TOPK; ++j) { all_s[t][j] = ts[j]; all_i[t][j] = ti[j]; }

    __shared__ float rs[256]; __shared__ int ri[256]; __shared__ int rt[256];
    int ptr = 0;
    __syncthreads();

    for (int round = 0; round < TOPK; ++round) {
        rs[t] = (ptr < TOPK) ? all_s[t][ptr] : -3.4e38f;
        ri[t] = (ptr < TOPK) ? all_i[t][ptr] : 0x7fffffff;
        rt[t] = t;
        __syncthreads();
        for (int s = 128; s > 0; s >>= 1) {
            if (t < s) {
                bool take = (rs[t + s] > rs[t]) ||
                            (rs[t + s] == rs[t] && ri[t + s] < ri[t]);
                if (take) { rs[t] = rs[t + s]; ri[t] = ri[t + s]; rt[t] = rt[t + s]; }
            }
            __syncthreads();
        }
        if (t == 0) {
            cs[((size_t)b * CH + c) * TOPK + round] = rs[0];
            ci[((size_t)b * CH + c) * TOPK + round] = ri[0];
        }
        if (t == rt[0]) ++ptr;                  // winner advances its head
        __syncthreads();                        // protect rs/rt from next round's writes
    }
}

// ---------------- K4: merge CH*10 candidates per row, write float(index) ----------------
__global__ void topk_final(const float* __restrict__ cs, const int* __restrict__ ci,
                           float* __restrict__ outIdx) {
    const int b = blockIdx.x;
    const int t = threadIdx.x;                  // 64 threads
    __shared__ float fs[CH * TOPK];
    __shared__ int   fi[CH * TOPK];
    for (int j = t; j < CH * TOPK; j += 64) {
        fs[j] = cs[(size_t)b * CH * TOPK + j];
        fi[j] = ci[(size_t)b * CH * TOPK + j];
    }
    __syncthreads();
    if (t == 0) {
        float ts[TOPK]; int ti[TOPK];
        #pragma unroll
        for (int j = 0; j < TOPK; ++j) { ts[j] = -3.4e38f; ti[j] = 0x7fffffff; }
        for (int e = 0; e < CH * TOPK; ++e) {
            float cv = fs[e]; int cidx = fi[e];
            if (cv > ts[TOPK - 1] || (cv == ts[TOPK - 1] && cidx < ti[TOPK - 1])) {
                #pragma unroll
                for (int j = 0; j < TOPK; ++j) {
                    bool g = (cv > ts[j]) || (cv == ts[j] && cidx < ti[j]);
                    float ns = g ? cv : ts[j]; int ni = g ? cidx : ti[j];
                    cv = g ? ts[j] : cv; cidx = g ? ti[j] : cidx;
                    ts[j] = ns; ti[j] = ni;
                }
            }
        }
        #pragma unroll
        for (int j = 0; j < TOPK; ++j) outIdx[b * TOPK + j] = (float)ti[j];
    }
}

extern "C" void kernel_launch(void* const* d_in, const int* in_sizes, int n_in,
                              void* d_out, int out_size, void* d_ws, size_t ws_size,
                              hipStream_t stream) {
    const float* T = (const float*)d_in[0];
    const float* S = (const float*)d_in[1];
    const int N = in_sizes[1] / D_DIM;          // 500000
    float* out = (float*)d_out;

    // ws layout: tHi[64*512]u16 | tLo[64*512]u16 | cand scores[64*CH*10]f32 | cand idx[64*CH*10]i32
    unsigned short* tHi = (unsigned short*)d_ws;
    unsigned short* tLo = tHi + B_TEXT * D_DIM;
    float* cs = (float*)(tLo + B_TEXT * D_DIM);
    int*   ci = (int*)(cs + B_TEXT * CH * TOPK);

    prep_text<<<B_TEXT, 64, 0, stream>>>(T, tHi, tLo);
    int nblk = (N + TILE_N - 1) / TILE_N;
    gemm_scores<<<nblk, 256, 0, stream>>>(S, tHi, tLo, out, N);
    dim3 g3(CH, B_TEXT);
    topk_part<<<g3, 256, 0, stream>>>(out, cs, ci, N);
    topk_final<<<B_TEXT, 64, 0, stream>>>(cs, ci, out + (size_t)B_TEXT * N);
}